// Round 14
// baseline (222.424 us; speedup 1.0000x reference)
//
#include <hip/hip_runtime.h>
#include <cstdint>
#include <cstddef>

#define NPTS 4096
#define KNN  16
#define INV_DEG (1.0f / 17.0f)
#define CAP  48   // knn per-point candidate buffer (entries [48..64) = slot staging)

typedef unsigned long long u64;
typedef unsigned int u32;
typedef float v2f __attribute__((ext_vector_type(2)));

// Raw keys: (f32bits(d2) << 32) | j. Interpreted as f64 this is
// order-isomorphic to (d2 asc, idx asc) for all finite d2 (see R11 notes).
// Sentinels below have exponent 0x7F8 (not 0x7FF) -> finite huge, sort last.
#define UNUSED_K 0x7F800000FFFFFFFFull
#define SELF_K   0x7F800000FFFFFFFEull

__device__ __forceinline__ double as_f64(u64 k) { return __longlong_as_double((long long)k); }

// ---------------------------------------------------------------------------
// K1: exact KNN (top-16 smallest d2, tie -> lower index) + fused enc1.
// UNCHANGED from the 215.1us best (125.3us, VALU 78%, occ 70%).
// R9 WIN (137->125): no LDS staging, candidates straight from global
// (96KB/batch L1/L2-hot), sq recomputed with EXACT sqi rn-sequence -> d2
// bit-identical; no scan barriers -> no phase-aligned stall bursts.
// Dead levers: R2 occupancy-granularity, R6 VALU cut (busy -6pts dur flat),
// R7 sc prefetch (-5us), R8 4pt/wave (+17us), R10 grid split (+17us).
// NOTE: measured VALU-issue ~3x hand count — unexplained without disasm;
// do not trust further VALU-trim theories without new evidence.
// Ledger: (R3) spill w/o launch_bounds; (R4) flush = LDS rank-select beats
// bitonic; (R11) f64 compares in flush; (R6) bootstrap kept.
// ---------------------------------------------------------------------------
__global__ __launch_bounds__(256) void knn_kernel(const float* __restrict__ feats,
                                                  const float* __restrict__ W1,
                                                  const float* __restrict__ b1,
                                                  int* __restrict__ nbr,
                                                  float* __restrict__ x1) {
#pragma clang fp contract(off)
  __shared__ u64 sbuf[4][2][64];  // 4 KB

  const int b = blockIdx.x >> 9;
  const int pbase = (blockIdx.x & 511) * 8;
  const float* fb = feats + (size_t)b * NPTS * 6;
  const int wave = threadIdx.x >> 6;
  const int lane = threadIdx.x & 63;

  int ip[2];
  float xi[2], yi[2], zi[2], sqi[2], tau[2];
  u64 slot[2];
  int cnt[2];
#pragma unroll
  for (int p = 0; p < 2; ++p) {
    ip[p] = pbase + wave * 2 + p;
    const float* fr = fb + (size_t)ip[p] * 6;
    xi[p] = fr[0]; yi[p] = fr[1]; zi[p] = fr[2];
    sqi[p] = __fadd_rn(__fadd_rn(__fmul_rn(xi[p], xi[p]), __fmul_rn(yi[p], yi[p])),
                       __fmul_rn(zi[p], zi[p]));
    tau[p] = __uint_as_float(0x7f800000u);
    slot[p] = UNUSED_K;
    cnt[p] = 0;
  }

  // LDS rank-select merge of {<=48 buffered} U {16 slots}, all raw keys.
  auto flush = [&](int p) {
    u64* wb = &sbuf[wave][p][0];
    if (lane >= cnt[p] && lane < CAP) wb[lane] = UNUSED_K;  // clear unused
    if (lane < KNN) wb[CAP + lane] = slot[p];               // stage slots
    u64 myk = wb[lane];
    if ((u32)myk == (u32)ip[p]) {  // neutralize self (sentinel lows != ip)
      myk = SELF_K;
      wb[lane] = SELF_K;
    }
    const double dm = as_f64(myk);
    int rank = 0;
#pragma unroll
    for (int m = 0; m < 64; m += 4) {
      const double k0 = as_f64(wb[m]), k1 = as_f64(wb[m + 1]);
      const double k2 = as_f64(wb[m + 2]), k3 = as_f64(wb[m + 3]);
      rank += (int)(k0 < dm) + (int)(k1 < dm) + (int)(k2 < dm) + (int)(k3 < dm);
    }
    if (rank < KNN) wb[rank] = myk;
    u64 s15 = wb[15];
    if (lane < KNN) slot[p] = wb[lane];
    tau[p] = __uint_as_float((u32)(s15 >> 32));  // raw hi bits ARE d2 bits
    cnt[p] = 0;
  };

  for (int jb = 0; jb < NPTS; jb += 64) {
    const int j = jb + lane;
    // direct global read: rows are 24B (8B-aligned) -> coalesced, L1/L2-hot.
    const float* fr = fb + (size_t)j * 6;
    const float cx = fr[0], cy = fr[1], cz = fr[2];
    // sq with the EXACT rn op sequence used for sqi (d2 bit-compat)
    const float csq = __fadd_rn(__fadd_rn(__fmul_rn(cx, cx), __fmul_rn(cy, cy)),
                                __fmul_rn(cz, cz));
    const v2f cx2 = {cx, cx}, cy2 = {cy, cy}, cz2 = {cz, cz}, sq2 = {csq, csq};
    v2f X = {xi[0], xi[1]};
    v2f Y = {yi[0], yi[1]};
    v2f Z = {zi[0], zi[1]};
    v2f SQ = {sqi[0], sqi[1]};
    v2f dot = X * cx2;
    dot = __builtin_elementwise_fma(Y, cy2, dot);
    dot = __builtin_elementwise_fma(Z, cz2, dot);
    v2f two = {2.0f, 2.0f};
    v2f d2v = (SQ + sq2) - two * dot;  // contract(off): rn each op
    float d2s[2] = {d2v.x, d2v.y};

    if (jb == 0) {
      // ---- BOOTSTRAP: rank-select the 64 fresh keys directly (R6) ----
#pragma unroll
      for (int p = 0; p < 2; ++p) {
        u64* wb = &sbuf[wave][p][0];
        u64 myk = ((u64)__float_as_uint(d2s[p]) << 32) | (u32)j;
        if ((u32)myk == (u32)ip[p]) myk = SELF_K;  // neutralize self
        wb[lane] = myk;
        const double dm = as_f64(myk);
        int rank = 0;
#pragma unroll
        for (int m = 0; m < 64; m += 4) {
          const double k0 = as_f64(wb[m]), k1 = as_f64(wb[m + 1]);
          const double k2 = as_f64(wb[m + 2]), k3 = as_f64(wb[m + 3]);
          rank += (int)(k0 < dm) + (int)(k1 < dm) + (int)(k2 < dm) + (int)(k3 < dm);
        }
        if (rank < KNN) wb[rank] = myk;  // unique keys -> unique ranks
        u64 s15 = wb[15];
        if (lane < KNN) slot[p] = wb[lane];
        tau[p] = __uint_as_float((u32)(s15 >> 32));
        // cnt[p] stays 0
      }
      continue;
    }

#pragma unroll
    for (int p = 0; p < 2; ++p) {
      const bool pred = d2s[p] <= tau[p];
      const u64 bal = __ballot(pred);
      if (bal) {
        const int npass = __popcll(bal);
        if (cnt[p] + npass > CAP) flush(p);
        const int pos = cnt[p] + (int)__builtin_amdgcn_mbcnt_hi(
                                      (u32)(bal >> 32),
                                      __builtin_amdgcn_mbcnt_lo((u32)bal, 0));
        const u64 key = ((u64)__float_as_uint(d2s[p]) << 32) | (u32)j;  // RAW
        if (npass <= CAP) {
          if (pred) sbuf[wave][p][pos] = key;
          cnt[p] += npass;
        } else {  // npass in (48,64]: pathological ties
          if (pred && pos < CAP) sbuf[wave][p][pos] = key;
          cnt[p] = CAP;
          flush(p);
          if (pred && pos >= CAP) sbuf[wave][p][pos - CAP] = key;
          cnt[p] = npass - CAP;
        }
      }
    }
  }
#pragma unroll
  for (int p = 0; p < 2; ++p) flush(p);  // final merge -> slots hold winners

  // ---- fused enc1: x1[n] = relu(((Σ_{nbr ∪ self} feats) @ W1)*inv_deg + b1)
  float* fsc = (float*)&sbuf[wave][0][0];  // wave-private scratch
  float w1r[6];
#pragma unroll
  for (int k = 0; k < 6; ++k) w1r[k] = W1[k * 64 + lane];
  const float b1r = b1[lane];

#pragma unroll
  for (int p = 0; p < 2; ++p) {
    const int n = b * NPTS + ip[p];
    const int row = (lane < KNN) ? (int)(u32)slot[p] : ip[p];
    if (lane < KNN)
      nbr[(size_t)n * KNN + lane] = row;  // for enc23's gather
    if (lane < 17) {
      const float* fr = fb + (size_t)row * 6;
      float2 r0 = *(const float2*)(fr);
      float2 r1 = *(const float2*)(fr + 2);
      float2 r2 = *(const float2*)(fr + 4);
      fsc[lane * 6 + 0] = r0.x; fsc[lane * 6 + 1] = r0.y;
      fsc[lane * 6 + 2] = r1.x; fsc[lane * 6 + 3] = r1.y;
      fsc[lane * 6 + 4] = r2.x; fsc[lane * 6 + 5] = r2.y;
    }
    __syncthreads();  // all waves execute both iterations: barriers match
    if (lane < 6) {
      float s = 0.f;
#pragma unroll
      for (int t = 0; t < 17; ++t) s += fsc[t * 6 + lane];
      fsc[102 + lane] = s;
    }
    __syncthreads();
    float s = 0.f;
#pragma unroll
    for (int k = 0; k < 6; ++k) s = fmaf(fsc[102 + k], w1r[k], s);
    x1[(size_t)n * 64 + lane] = fmaxf(fmaf(s, INV_DEG, b1r), 0.f);
    __syncthreads();  // protect fsc reuse for p=1
  }
}

// ---------------------------------------------------------------------------
// T2 v6 (R12): R11 structure (readlane GEMM2, xs deleted) + weight tile
// DOUBLE-BUFFERED. Rationale: R11 shrank GEMM2's per-tile compute phase, so
// the 24 tile barriers + serial load->store->sync->compute chain are now a
// larger runtime fraction; dbuf halves barriers (24->12) and issues each
// tile's global loads one tile early (latency hides under prev tile's FMAs).
// R4's dbuf-neutral verdict was on the OLD xs-heavy structure — conditions
// changed. LDS 12->20KB, still 8 blocks/CU. FP order unchanged ->
// bit-identical. (R1 blocking FAIL; R5 weights-from-global FAIL; R11
// readlane WIN -3us.)
// ---------------------------------------------------------------------------
__global__ __launch_bounds__(256) void enc23_kernel(const float* __restrict__ x1,
                                                    const int* __restrict__ nbr,
                                                    const float* __restrict__ W2,
                                                    const float* __restrict__ b2,
                                                    const float* __restrict__ Wf,
                                                    const float* __restrict__ bf,
                                                    float* __restrict__ out) {
  __shared__ float a1s[16][64];   // 4 KB
  __shared__ v2f wt[2][16][64];   // 16 KB double-buffered weight tile
  const int tid = threadIdx.x;
  const int n0 = blockIdx.x * 16;
  const int gb = n0 & ~(NPTS - 1);
  const int wave = tid >> 6, lane = tid & 63;

  // gather + aggregate x1 for 16 points (16 threads/point, float4 channels)
  {
    const int p = tid >> 4, c4 = tid & 15;
    const int n = n0 + p;
    const int* nb = nbr + (size_t)n * KNN;
    float4 s = ((const float4*)(x1 + (size_t)n * 64))[c4];
#pragma unroll
    for (int t = 0; t < KNN; ++t) {
      float4 v = ((const float4*)(x1 + (size_t)(gb + nb[t]) * 64))[c4];
      s.x += v.x; s.y += v.y; s.z += v.z; s.w += v.w;
    }
    *((float4*)&a1s[p][c4 * 4]) = s;
  }

  const int p0 = wave * 4;
  const float bx = b2[lane], by = b2[lane + 64];

  // weight-tile staging: 1024 v2f per 16-row tile, 4 per thread, via regs
  v2f wreg[4];
  auto loadW = [&](const float* __restrict__ W, int kt) {
#pragma unroll
    for (int i = 0; i < 4; ++i) {
      const int e = tid + 256 * i;
      const int k = e >> 6, l = e & 63;
      wreg[i].x = W[(kt + k) * 128 + l];
      wreg[i].y = W[(kt + k) * 128 + 64 + l];
    }
  };
  auto storeW = [&](int buf) {
#pragma unroll
    for (int i = 0; i < 4; ++i) {
      const int e = tid + 256 * i;
      wt[buf][e >> 6][e & 63] = wreg[i];
    }
  };

  loadW(W2, 0);
  storeW(0);
  __syncthreads();  // covers gather->a1s AND wt[0]

  // ---- GEMM1: x2 = relu((a1@W2)*inv_deg + b2), 4 k-tiles, dbuf ----
  v2f acc[4];
#pragma unroll
  for (int i = 0; i < 4; ++i) acc[i] = (v2f){0, 0};
  for (int kt_i = 0; kt_i < 4; ++kt_i) {
    if (kt_i < 3) loadW(W2, (kt_i + 1) * 16);  // issue early: hides under FMAs
    const int cur = kt_i & 1;
    const int kt = kt_i * 16;
    for (int kk = 0; kk < 16; kk += 4) {
      float4 a[4];
#pragma unroll
      for (int i = 0; i < 4; ++i) a[i] = *(const float4*)&a1s[p0 + i][kt + kk];
#pragma unroll
      for (int j = 0; j < 4; ++j) {
        const v2f w = wt[cur][kk + j][lane];
#pragma unroll
        for (int i = 0; i < 4; ++i) {
          const float e = j == 0 ? a[i].x : j == 1 ? a[i].y : j == 2 ? a[i].z
                                                                     : a[i].w;
          v2f v = {e, e};
          acc[i] = __builtin_elementwise_fma(v, w, acc[i]);
        }
      }
    }
    // buf cur^1's readers all passed the previous end-of-tile barrier.
    if (kt_i < 3) storeW(cur ^ 1);
    __syncthreads();
  }

  // x2 stays in registers: thread t holds x2[p0+i][t] (r0), x2[p0+i][t+64]
  // (r1). Same relu/bias math as before.
  float r0[4], r1[4];
#pragma unroll
  for (int pi = 0; pi < 4; ++pi) {
    r0[pi] = fmaxf(fmaf(acc[pi].x, INV_DEG, bx), 0.f);
    r1[pi] = fmaxf(fmaf(acc[pi].y, INV_DEG, by), 0.f);
  }

  // ---- GEMM2: out = x2@Wf + bf; activations via readlane, Wf dbuf'd ----
  // GEMM1 ended with a barrier; all wt reads done -> buf0 free for Wf tile 0.
  loadW(Wf, 0);
  storeW(0);
  __syncthreads();

  v2f facc[4];
#pragma unroll
  for (int i = 0; i < 4; ++i) facc[i] = (v2f){0, 0};
  for (int jt_i = 0; jt_i < 8; ++jt_i) {
    if (jt_i < 7) loadW(Wf, (jt_i + 1) * 16);
    const int cur = jt_i & 1;
    const int half = jt_i >> 2;        // k in [0,64) -> r0, [64,128) -> r1
    const int klbase = (jt_i & 3) * 16;  // lane index base within the half
#pragma unroll
    for (int jj = 0; jj < 16; ++jj) {
      const v2f w = wt[cur][jj][lane];
      const int kl = klbase + jj;  // wave-uniform lane index
#pragma unroll
      for (int i = 0; i < 4; ++i) {
        const float src = half == 0 ? r0[i] : r1[i];
        const float e = __uint_as_float(
            (u32)__builtin_amdgcn_readlane((int)__float_as_uint(src), kl));
        v2f v = {e, e};
        facc[i] = __builtin_elementwise_fma(v, w, facc[i]);
      }
    }
    if (jt_i < 7) storeW(cur ^ 1);
    __syncthreads();
  }
  const float fx = bf[lane], fy = bf[lane + 64];
#pragma unroll
  for (int pi = 0; pi < 4; ++pi) {
    float* row = out + (size_t)(n0 + p0 + pi) * 128;
    row[lane] = facc[pi].x + fx;
    row[lane + 64] = facc[pi].y + fy;
  }
}

// ---------------------------------------------------------------------------
// Workspace: nbr@0 (2MB), x1@2MB (8MB). x2 never materialized anywhere.
// ---------------------------------------------------------------------------
extern "C" void kernel_launch(void* const* d_in, const int* in_sizes, int n_in,
                              void* d_out, int out_size, void* d_ws, size_t ws_size,
                              hipStream_t stream) {
  const float* feats = (const float*)d_in[0];
  const float* W1 = (const float*)d_in[1];
  const float* b1 = (const float*)d_in[2];
  const float* W2 = (const float*)d_in[3];
  const float* b2 = (const float*)d_in[4];
  const float* Wf = (const float*)d_in[5];
  const float* bf = (const float*)d_in[6];
  float* out = (float*)d_out;

  char* ws = (char*)d_ws;
  int* nbr = (int*)ws;
  float* x1 = (float*)(ws + (size_t)(2 << 20));

  knn_kernel<<<4096, 256, 0, stream>>>(feats, W1, b1, nbr, x1);
  enc23_kernel<<<2048, 256, 0, stream>>>(x1, nbr, W2, b2, Wf, bf, out);
}

// Round 15
// 214.078 us; speedup vs baseline: 1.0390x; 1.0390x over previous
//
#include <hip/hip_runtime.h>
#include <cstdint>
#include <cstddef>

#define NPTS 4096
#define KNN  16
#define INV_DEG (1.0f / 17.0f)
#define CAP  48   // knn per-point candidate buffer (entries [48..64) = slot staging)

typedef unsigned long long u64;
typedef unsigned int u32;
typedef float v2f __attribute__((ext_vector_type(2)));

// Raw keys: (f32bits(d2) << 32) | j. Interpreted as f64 this is
// order-isomorphic to (d2 asc, idx asc) for all finite d2 (see R11 notes).
// Sentinels below have exponent 0x7F8 (not 0x7FF) -> finite huge, sort last.
#define UNUSED_K 0x7F800000FFFFFFFFull
#define SELF_K   0x7F800000FFFFFFFEull

__device__ __forceinline__ double as_f64(u64 k) { return __longlong_as_double((long long)k); }

// ---------------------------------------------------------------------------
// K1: exact KNN (top-16 smallest d2, tie -> lower index) + fused enc1.
// FINAL FORM (measured 125.3us, VALU 78%, occ 70%, HBM 1.3%, 0 conflicts).
// R9 WIN (137->125): no LDS staging, candidates straight from global
// (96KB/batch L1/L2-hot), sq recomputed with EXACT sqi rn-sequence -> d2
// bit-identical; no scan barriers -> no phase-aligned stall bursts.
// Dead levers: R2 occupancy-granularity, R6 VALU cut (busy -6pts dur flat),
// R7 sc prefetch (-5us), R8 4pt/wave (+17us), R10 grid split (+17us).
// Residual = per-step serial dependency (d2 chain -> ballot -> scalar
// branch) intrinsic to the exact streaming-filter algorithm.
// Ledger: (R3) spill w/o launch_bounds; (R4) flush = LDS rank-select beats
// bitonic; (R11) f64 compares in flush; (R6) bootstrap kept.
// ---------------------------------------------------------------------------
__global__ __launch_bounds__(256) void knn_kernel(const float* __restrict__ feats,
                                                  const float* __restrict__ W1,
                                                  const float* __restrict__ b1,
                                                  int* __restrict__ nbr,
                                                  float* __restrict__ x1) {
#pragma clang fp contract(off)
  __shared__ u64 sbuf[4][2][64];  // 4 KB

  const int b = blockIdx.x >> 9;
  const int pbase = (blockIdx.x & 511) * 8;
  const float* fb = feats + (size_t)b * NPTS * 6;
  const int wave = threadIdx.x >> 6;
  const int lane = threadIdx.x & 63;

  int ip[2];
  float xi[2], yi[2], zi[2], sqi[2], tau[2];
  u64 slot[2];
  int cnt[2];
#pragma unroll
  for (int p = 0; p < 2; ++p) {
    ip[p] = pbase + wave * 2 + p;
    const float* fr = fb + (size_t)ip[p] * 6;
    xi[p] = fr[0]; yi[p] = fr[1]; zi[p] = fr[2];
    sqi[p] = __fadd_rn(__fadd_rn(__fmul_rn(xi[p], xi[p]), __fmul_rn(yi[p], yi[p])),
                       __fmul_rn(zi[p], zi[p]));
    tau[p] = __uint_as_float(0x7f800000u);
    slot[p] = UNUSED_K;
    cnt[p] = 0;
  }

  // LDS rank-select merge of {<=48 buffered} U {16 slots}, all raw keys.
  auto flush = [&](int p) {
    u64* wb = &sbuf[wave][p][0];
    if (lane >= cnt[p] && lane < CAP) wb[lane] = UNUSED_K;  // clear unused
    if (lane < KNN) wb[CAP + lane] = slot[p];               // stage slots
    u64 myk = wb[lane];
    if ((u32)myk == (u32)ip[p]) {  // neutralize self (sentinel lows != ip)
      myk = SELF_K;
      wb[lane] = SELF_K;
    }
    const double dm = as_f64(myk);
    int rank = 0;
#pragma unroll
    for (int m = 0; m < 64; m += 4) {
      const double k0 = as_f64(wb[m]), k1 = as_f64(wb[m + 1]);
      const double k2 = as_f64(wb[m + 2]), k3 = as_f64(wb[m + 3]);
      rank += (int)(k0 < dm) + (int)(k1 < dm) + (int)(k2 < dm) + (int)(k3 < dm);
    }
    if (rank < KNN) wb[rank] = myk;
    u64 s15 = wb[15];
    if (lane < KNN) slot[p] = wb[lane];
    tau[p] = __uint_as_float((u32)(s15 >> 32));  // raw hi bits ARE d2 bits
    cnt[p] = 0;
  };

  for (int jb = 0; jb < NPTS; jb += 64) {
    const int j = jb + lane;
    // direct global read: rows are 24B (8B-aligned) -> coalesced, L1/L2-hot.
    const float* fr = fb + (size_t)j * 6;
    const float cx = fr[0], cy = fr[1], cz = fr[2];
    // sq with the EXACT rn op sequence used for sqi (d2 bit-compat)
    const float csq = __fadd_rn(__fadd_rn(__fmul_rn(cx, cx), __fmul_rn(cy, cy)),
                                __fmul_rn(cz, cz));
    const v2f cx2 = {cx, cx}, cy2 = {cy, cy}, cz2 = {cz, cz}, sq2 = {csq, csq};
    v2f X = {xi[0], xi[1]};
    v2f Y = {yi[0], yi[1]};
    v2f Z = {zi[0], zi[1]};
    v2f SQ = {sqi[0], sqi[1]};
    v2f dot = X * cx2;
    dot = __builtin_elementwise_fma(Y, cy2, dot);
    dot = __builtin_elementwise_fma(Z, cz2, dot);
    v2f two = {2.0f, 2.0f};
    v2f d2v = (SQ + sq2) - two * dot;  // contract(off): rn each op
    float d2s[2] = {d2v.x, d2v.y};

    if (jb == 0) {
      // ---- BOOTSTRAP: rank-select the 64 fresh keys directly (R6) ----
#pragma unroll
      for (int p = 0; p < 2; ++p) {
        u64* wb = &sbuf[wave][p][0];
        u64 myk = ((u64)__float_as_uint(d2s[p]) << 32) | (u32)j;
        if ((u32)myk == (u32)ip[p]) myk = SELF_K;  // neutralize self
        wb[lane] = myk;
        const double dm = as_f64(myk);
        int rank = 0;
#pragma unroll
        for (int m = 0; m < 64; m += 4) {
          const double k0 = as_f64(wb[m]), k1 = as_f64(wb[m + 1]);
          const double k2 = as_f64(wb[m + 2]), k3 = as_f64(wb[m + 3]);
          rank += (int)(k0 < dm) + (int)(k1 < dm) + (int)(k2 < dm) + (int)(k3 < dm);
        }
        if (rank < KNN) wb[rank] = myk;  // unique keys -> unique ranks
        u64 s15 = wb[15];
        if (lane < KNN) slot[p] = wb[lane];
        tau[p] = __uint_as_float((u32)(s15 >> 32));
        // cnt[p] stays 0
      }
      continue;
    }

#pragma unroll
    for (int p = 0; p < 2; ++p) {
      const bool pred = d2s[p] <= tau[p];
      const u64 bal = __ballot(pred);
      if (bal) {
        const int npass = __popcll(bal);
        if (cnt[p] + npass > CAP) flush(p);
        const int pos = cnt[p] + (int)__builtin_amdgcn_mbcnt_hi(
                                      (u32)(bal >> 32),
                                      __builtin_amdgcn_mbcnt_lo((u32)bal, 0));
        const u64 key = ((u64)__float_as_uint(d2s[p]) << 32) | (u32)j;  // RAW
        if (npass <= CAP) {
          if (pred) sbuf[wave][p][pos] = key;
          cnt[p] += npass;
        } else {  // npass in (48,64]: pathological ties
          if (pred && pos < CAP) sbuf[wave][p][pos] = key;
          cnt[p] = CAP;
          flush(p);
          if (pred && pos >= CAP) sbuf[wave][p][pos - CAP] = key;
          cnt[p] = npass - CAP;
        }
      }
    }
  }
#pragma unroll
  for (int p = 0; p < 2; ++p) flush(p);  // final merge -> slots hold winners

  // ---- fused enc1: x1[n] = relu(((Σ_{nbr ∪ self} feats) @ W1)*inv_deg + b1)
  float* fsc = (float*)&sbuf[wave][0][0];  // wave-private scratch
  float w1r[6];
#pragma unroll
  for (int k = 0; k < 6; ++k) w1r[k] = W1[k * 64 + lane];
  const float b1r = b1[lane];

#pragma unroll
  for (int p = 0; p < 2; ++p) {
    const int n = b * NPTS + ip[p];
    const int row = (lane < KNN) ? (int)(u32)slot[p] : ip[p];
    if (lane < KNN)
      nbr[(size_t)n * KNN + lane] = row;  // for enc23's gather
    if (lane < 17) {
      const float* fr = fb + (size_t)row * 6;
      float2 r0 = *(const float2*)(fr);
      float2 r1 = *(const float2*)(fr + 2);
      float2 r2 = *(const float2*)(fr + 4);
      fsc[lane * 6 + 0] = r0.x; fsc[lane * 6 + 1] = r0.y;
      fsc[lane * 6 + 2] = r1.x; fsc[lane * 6 + 3] = r1.y;
      fsc[lane * 6 + 4] = r2.x; fsc[lane * 6 + 5] = r2.y;
    }
    __syncthreads();  // all waves execute both iterations: barriers match
    if (lane < 6) {
      float s = 0.f;
#pragma unroll
      for (int t = 0; t < 17; ++t) s += fsc[t * 6 + lane];
      fsc[102 + lane] = s;
    }
    __syncthreads();
    float s = 0.f;
#pragma unroll
    for (int k = 0; k < 6; ++k) s = fmaf(fsc[102 + k], w1r[k], s);
    x1[(size_t)n * 64 + lane] = fmaxf(fmaf(s, INV_DEG, b1r), 0.f);
    __syncthreads();  // protect fsc reuse for p=1
  }
}

// ---------------------------------------------------------------------------
// T2 v5 (R11, FINAL FORM — best measured): enc2+enc3, GEMM2 activations in
// registers via v_readlane (xs deleted, LDS 12KB). WIN -3us vs R10 form.
// Dead levers: R1 reg blocking (+19us), R4 dbuf-old (neutral), R5 weights-
// from-global (+15us), R12 dbuf-new (+7us) — dbuf is net-negative in BOTH
// structures; single-buffered wt + readlane is the local optimum.
// ---------------------------------------------------------------------------
__global__ __launch_bounds__(256) void enc23_kernel(const float* __restrict__ x1,
                                                    const int* __restrict__ nbr,
                                                    const float* __restrict__ W2,
                                                    const float* __restrict__ b2,
                                                    const float* __restrict__ Wf,
                                                    const float* __restrict__ bf,
                                                    float* __restrict__ out) {
  __shared__ float a1s[16][64];  // 4 KB
  __shared__ v2f wt[16][64];     // 8 KB streaming weight tile
  const int tid = threadIdx.x;
  const int n0 = blockIdx.x * 16;
  const int gb = n0 & ~(NPTS - 1);
  const int wave = tid >> 6, lane = tid & 63;

  // gather + aggregate x1 for 16 points (16 threads/point, float4 channels)
  {
    const int p = tid >> 4, c4 = tid & 15;
    const int n = n0 + p;
    const int* nb = nbr + (size_t)n * KNN;
    float4 s = ((const float4*)(x1 + (size_t)n * 64))[c4];
#pragma unroll
    for (int t = 0; t < KNN; ++t) {
      float4 v = ((const float4*)(x1 + (size_t)(gb + nb[t]) * 64))[c4];
      s.x += v.x; s.y += v.y; s.z += v.z; s.w += v.w;
    }
    *((float4*)&a1s[p][c4 * 4]) = s;
  }

  const int p0 = wave * 4;
  const float bx = b2[lane], by = b2[lane + 64];

  // ---- GEMM1: x2 = relu((a1@W2)*inv_deg + b2), W2 streamed in 4 tiles ----
  v2f acc[4];
#pragma unroll
  for (int i = 0; i < 4; ++i) acc[i] = (v2f){0, 0};
  for (int kt = 0; kt < 64; kt += 16) {
    __syncthreads();  // prev tile readers done (also covers initial gather)
#pragma unroll
    for (int i = 0; i < 4; ++i) {
      const int e = tid + 256 * i;  // 1024 v2f
      const int k = e >> 6, l = e & 63;
      v2f w;
      w.x = W2[(kt + k) * 128 + l];
      w.y = W2[(kt + k) * 128 + 64 + l];
      wt[k][l] = w;
    }
    __syncthreads();
    for (int kk = 0; kk < 16; kk += 4) {
      float4 a[4];
#pragma unroll
      for (int i = 0; i < 4; ++i) a[i] = *(const float4*)&a1s[p0 + i][kt + kk];
#pragma unroll
      for (int j = 0; j < 4; ++j) {
        const v2f w = wt[kk + j][lane];
#pragma unroll
        for (int i = 0; i < 4; ++i) {
          const float e = j == 0 ? a[i].x : j == 1 ? a[i].y : j == 2 ? a[i].z
                                                                     : a[i].w;
          v2f v = {e, e};
          acc[i] = __builtin_elementwise_fma(v, w, acc[i]);
        }
      }
    }
  }

  // x2 values stay in registers: thread t holds x2[p0+i][t] (r0) and
  // x2[p0+i][t+64] (r1). Same relu/bias math as the old xs store.
  float r0[4], r1[4];
#pragma unroll
  for (int pi = 0; pi < 4; ++pi) {
    r0[pi] = fmaxf(fmaf(acc[pi].x, INV_DEG, bx), 0.f);
    r1[pi] = fmaxf(fmaf(acc[pi].y, INV_DEG, by), 0.f);
  }

  // ---- GEMM2: out = x2@Wf + bf. Activation via v_readlane (uniform idx);
  // only Wf goes through LDS. k ascends 0..127 -> fma order == old version.
  v2f facc[4];
#pragma unroll
  for (int i = 0; i < 4; ++i) facc[i] = (v2f){0, 0};
#pragma unroll
  for (int half = 0; half < 2; ++half) {
    for (int jt_i = 0; jt_i < 4; ++jt_i) {
      const int jt = (half * 4 + jt_i) * 16;
      __syncthreads();  // prev tile readers done
#pragma unroll
      for (int i = 0; i < 4; ++i) {
        const int e = tid + 256 * i;
        const int j = e >> 6, l = e & 63;
        v2f w;
        w.x = Wf[(jt + j) * 128 + l];
        w.y = Wf[(jt + j) * 128 + 64 + l];
        wt[j][l] = w;
      }
      __syncthreads();
      const int klbase = jt_i * 16;  // (jt & 63)
#pragma unroll
      for (int jj = 0; jj < 16; ++jj) {
        const v2f w = wt[jj][lane];
        const int kl = klbase + jj;  // wave-uniform lane index
#pragma unroll
        for (int i = 0; i < 4; ++i) {
          const float src = half == 0 ? r0[i] : r1[i];  // compile-time select
          const float e = __uint_as_float(
              (u32)__builtin_amdgcn_readlane((int)__float_as_uint(src), kl));
          v2f v = {e, e};
          facc[i] = __builtin_elementwise_fma(v, w, facc[i]);
        }
      }
    }
  }
  const float fx = bf[lane], fy = bf[lane + 64];
#pragma unroll
  for (int pi = 0; pi < 4; ++pi) {
    float* row = out + (size_t)(n0 + p0 + pi) * 128;
    row[lane] = facc[pi].x + fx;
    row[lane + 64] = facc[pi].y + fy;
  }
}

// ---------------------------------------------------------------------------
// Workspace: nbr@0 (2MB), x1@2MB (8MB). x2 never materialized anywhere.
// ---------------------------------------------------------------------------
extern "C" void kernel_launch(void* const* d_in, const int* in_sizes, int n_in,
                              void* d_out, int out_size, void* d_ws, size_t ws_size,
                              hipStream_t stream) {
  const float* feats = (const float*)d_in[0];
  const float* W1 = (const float*)d_in[1];
  const float* b1 = (const float*)d_in[2];
  const float* W2 = (const float*)d_in[3];
  const float* b2 = (const float*)d_in[4];
  const float* Wf = (const float*)d_in[5];
  const float* bf = (const float*)d_in[6];
  float* out = (float*)d_out;

  char* ws = (char*)d_ws;
  int* nbr = (int*)ws;
  float* x1 = (float*)(ws + (size_t)(2 << 20));

  knn_kernel<<<4096, 256, 0, stream>>>(feats, W1, b1, nbr, x1);
  enc23_kernel<<<2048, 256, 0, stream>>>(x1, nbr, W2, b2, Wf, bf, out);
}